// Round 20
// baseline (486.010 us; speedup 1.0000x reference)
//
#include <hip/hip_runtime.h>
#include <hip/hip_fp16.h>

#define N_ROWS 65536
#define D_COLS 1024
#define M_ROWS 32768
#define QROWS  16384   // rows per scatter pass (64KB f32 LDS)

using u32 = unsigned int;
using u16 = unsigned short;
typedef float f32x4 __attribute__((ext_vector_type(4)));   // native vecs for nontemporal
typedef int   i32x4 __attribute__((ext_vector_type(4)));

static __device__ __forceinline__ __half2 u32_as_half2(u32 w) {
    union { u32 u; __half2 h; } c; c.u = w; return c.h;
}

// ---- ws[0] = 0 (abs-max accumulator) ----
__global__ void init_ws_k(u32* ws) {
    if (threadIdx.x == 0 && blockIdx.x == 0) ws[0] = 0u;
}

// ---- 64x64-tile transpose+pack: packed[j][i] = (u16)idx[i][j] | fp16(upd*scl)<<16 ----
__global__ __launch_bounds__(256) void t_pack_k(const int* __restrict__ idx,
                                                const float* __restrict__ upd,
                                                const float* __restrict__ scl,
                                                u32* __restrict__ packed) {
    __shared__ u32   sidx[64][65];
    __shared__ float supd[64][65];
    const int swz = (int)(blockIdx.x & 7) * 1024 + (int)(blockIdx.x >> 3); // 8192%8==0
    const int i0 = (swz & 511) * 64;              // i-tile INNER (512 i-tiles)
    const int j0 = (swz >> 9) * 64;               // j-tile outer (16 j-tiles)
    const int t = threadIdx.x;

    {
        const int rr = t >> 2, c4 = t & 3;
        const int*   ip = idx + (size_t)(i0 + rr) * D_COLS + j0;
        const float* up = upd + (size_t)(i0 + rr) * D_COLS + j0;
        #pragma unroll
        for (int cq = 0; cq < 4; ++cq) {
            const int jc = cq * 16 + c4 * 4;
            const i32x4 iv = __builtin_nontemporal_load((const i32x4*)(ip + jc));
            const f32x4 uv = __builtin_nontemporal_load((const f32x4*)(up + jc));
            sidx[rr][jc] = (u32)iv.x; sidx[rr][jc+1] = (u32)iv.y;
            sidx[rr][jc+2] = (u32)iv.z; sidx[rr][jc+3] = (u32)iv.w;
            supd[rr][jc] = uv.x; supd[rr][jc+1] = uv.y;
            supd[rr][jc+2] = uv.z; supd[rr][jc+3] = uv.w;
        }
    }
    __syncthreads();

    {
        const int jj = t >> 2, seg = t & 3;
        const __half hs = __float2half(scl[j0 + jj]);   // exact fp16 scale
        u32 w16[16];
        #pragma unroll
        for (int p = 0; p < 16; ++p) {
            const int r = seg * 16 + p;
            const __half hv = __hmul(__float2half(supd[r][jj]), hs);  // fp16 mult = ref
            w16[p] = (sidx[r][jj] & 0xffffu) | ((u32)__half_as_ushort(hv) << 16);
        }
        u32* d = packed + (size_t)(j0 + jj) * M_ROWS + i0 + seg * 16;
        ((uint4*)d)[0] = uint4{w16[0],  w16[1],  w16[2],  w16[3]};
        ((uint4*)d)[1] = uint4{w16[4],  w16[5],  w16[6],  w16[7]};
        ((uint4*)d)[2] = uint4{w16[8],  w16[9],  w16[10], w16[11]};
        ((uint4*)d)[3] = uint4{w16[12], w16[13], w16[14], w16[15]};
    }
}

// ---- per (column j, quarter h): zero 64KB LDS, scan packed column, GUARDED ds_add
//      (33.5M active lane-atomics at ~3.4cy each: the measured wall), fp16 write. ----
__global__ __launch_bounds__(1024) void scatter_q_k(const u32* __restrict__ packed,
                                                    __half* __restrict__ sumT) {
    __shared__ float acc[QROWS];                  // 64 KB -> 2 blocks/CU
    const int bid = (blockIdx.x & 7) * 512 + (blockIdx.x >> 3);  // bijective, 4096%8==0
    const int j = bid >> 2;                       // column 0..1023
    const int h = bid & 3;                        // row quarter
    const int tid = threadIdx.x;

    float4* a4 = (float4*)acc;
    #pragma unroll
    for (int k = 0; k < 4; ++k) a4[k * 1024 + tid] = float4{0.f, 0.f, 0.f, 0.f};

    const i32x4* col4 = (const i32x4*)(packed + (size_t)j * M_ROWS);  // 8192 int4
    __syncthreads();

    #pragma unroll
    for (int k = 0; k < 8; ++k) {
        const i32x4 e4 = col4[k * 1024 + tid];
        const u32 e[4] = {(u32)e4.x, (u32)e4.y, (u32)e4.z, (u32)e4.w};
        #pragma unroll
        for (int q = 0; q < 4; ++q) {
            const int r = (int)(e[q] & 0xffffu);
            if ((r >> 14) == h)   // guarded: inactive lanes issue no atomic lane-op
                atomicAdd(&acc[r & (QROWS - 1)],
                          __half2float(__ushort_as_half((u16)(e[q] >> 16))));
        }
    }
    __syncthreads();

    uint4* dst4 = (uint4*)(sumT + (size_t)j * N_ROWS + h * QROWS);
    #pragma unroll
    for (int o = 0; o < 2; ++o) {
        const int base = o * 8192 + tid * 8;
        const float4 f0 = *(const float4*)&acc[base];
        const float4 f1 = *(const float4*)&acc[base + 4];
        const __half2 h0 = __floats2half2_rn(f0.x, f0.y);
        const __half2 h1 = __floats2half2_rn(f0.z, f0.w);
        const __half2 h2 = __floats2half2_rn(f1.x, f1.y);
        const __half2 h3 = __floats2half2_rn(f1.z, f1.w);
        dst4[o * 1024 + tid] = uint4{*(const u32*)&h0, *(const u32*)&h1,
                                     *(const u32*)&h2, *(const u32*)&h3};
    }
}

// ---- 128x64 tiles: out = var*s + sumT^T. sumT staged as RAW fp16 row-pairs
//      (__half2 LDS): 16 b32 writes + 8 b128 reads per thread (was 32+8) —
//      LDS issue was finalize's binding term per the R13-R18 issue model. ----
__global__ __launch_bounds__(256) void finalize_k(const int* __restrict__ var,
                                                  const __half* __restrict__ sumT,
                                                  const float* __restrict__ var_scale,
                                                  float* __restrict__ outf,
                                                  u32* __restrict__ ws) {
    __shared__ __half2 smh[64][68];               // [row-pair][col], 17 KB
    __shared__ float wmax[4];
    const int swz = (int)(blockIdx.x & 7) * 1024 + (int)(blockIdx.x >> 3); // 8192%8==0
    const int r0 = (swz & 511) * 128;             // r-tile INNER (512 r-tiles of 128)
    const int j0 = (swz >> 9) * 64;               // j-tile outer (16 j-tiles)
    const int tid = threadIdx.x;
    const float s = var_scale[0];

    // stage: thread (jj = tid>>2, seg = tid&3) loads 32 halfs of col jj (4 NT b128)
    {
        const int jj = tid >> 2, seg = tid & 3;
        const __half* colp = sumT + (size_t)(j0 + jj) * N_ROWS + r0 + seg * 32;
        #pragma unroll
        for (int q = 0; q < 4; ++q) {
            const i32x4 w = __builtin_nontemporal_load((const i32x4*)colp + q);
            const u32 w0 = (u32)w.x, w1 = (u32)w.y, w2 = (u32)w.z, w3 = (u32)w.w;
            smh[seg * 16 + q * 4 + 0][jj] = u32_as_half2(w0);
            smh[seg * 16 + q * 4 + 1][jj] = u32_as_half2(w1);
            smh[seg * 16 + q * 4 + 2][jj] = u32_as_half2(w2);
            smh[seg * 16 + q * 4 + 3][jj] = u32_as_half2(w3);
        }
    }
    __syncthreads();

    float m = 0.f;
    #pragma unroll
    for (int k = 0; k < 8; ++k) {
        const int l = k * 256 + tid;              // 0..2047 int4 units
        const int rr = l >> 4, c4 = l & 15;
        const i32x4 v = __builtin_nontemporal_load(
            (const i32x4*)(var + (size_t)(r0 + rr) * D_COLS + j0) + c4);
        // one b128 LDS read: 4 half2 pairs (rows 2*(rr>>1), +1) x cols c4*4..+3
        const __half2* hp = &smh[rr >> 1][c4 * 4];
        const __half2 p0 = hp[0], p1 = hp[1], p2 = hp[2], p3 = hp[3];
        const bool hi = (rr & 1) != 0;
        float4 o;
        o.x = (float)v.x * s + (hi ? __high2float(p0) : __low2float(p0));
        o.y = (float)v.y * s + (hi ? __high2float(p1) : __low2float(p1));
        o.z = (float)v.z * s + (hi ? __high2float(p2) : __low2float(p2));
        o.w = (float)v.w * s + (hi ? __high2float(p3) : __low2float(p3));
        ((float4*)(outf + (size_t)(r0 + rr) * D_COLS + j0))[c4] = o;
        m = fmaxf(m, fmaxf(fmaxf(fabsf(o.x), fabsf(o.y)),
                           fmaxf(fabsf(o.z), fabsf(o.w))));
    }
    for (int off = 32; off; off >>= 1) m = fmaxf(m, __shfl_xor(m, off));
    if ((tid & 63) == 0) wmax[tid >> 6] = m;
    __syncthreads();
    if (tid == 0) {
        m = fmaxf(fmaxf(wmax[0], wmax[1]), fmaxf(wmax[2], wmax[3]));
        atomicMax(ws, __float_as_uint(m));
    }
}

// ---- y = clip(rint(out*127/max)): finalize's tile map REVERSED within each XCD
//      band, so quant first re-reads the out-tiles finalize wrote last (L3-hot). ----
__global__ __launch_bounds__(256) void quant_k(const float* __restrict__ outf,
                                               float* __restrict__ y,
                                               const u32* __restrict__ ws,
                                               float* __restrict__ scale_out) {
    const float mx = __uint_as_float(ws[0]);
    const float inv = 127.0f / mx;
    const int i_rev = 1023 - (int)(blockIdx.x >> 3);
    const int swz = (int)(blockIdx.x & 7) * 1024 + i_rev;
    const int r0 = (swz & 511) * 128;
    const int j0 = (swz >> 9) * 64;
    const int tid = threadIdx.x;
    if (blockIdx.x == 0 && tid == 0) scale_out[0] = mx / 127.0f;
    #pragma unroll
    for (int k = 0; k < 8; ++k) {
        const int l = k * 256 + tid;
        const int rr = l >> 4, c4 = l & 15;
        const size_t off = (size_t)(r0 + rr) * D_COLS + j0 + c4 * 4;
        const float4 v = *(const float4*)(outf + off);
        f32x4 o;
        o.x = fminf(fmaxf(rintf(v.x * inv), -128.f), 127.f);
        o.y = fminf(fmaxf(rintf(v.y * inv), -128.f), 127.f);
        o.z = fminf(fmaxf(rintf(v.z * inv), -128.f), 127.f);
        o.w = fminf(fmaxf(rintf(v.w * inv), -128.f), 127.f);
        __builtin_nontemporal_store(o, (f32x4*)(y + off));   // y never re-read
    }
}

extern "C" void kernel_launch(void* const* d_in, const int* in_sizes, int n_in,
                              void* d_out, int out_size, void* d_ws, size_t ws_size,
                              hipStream_t stream) {
    const int*   var       = (const int*)d_in[0];     // int8 transported as int32
    const float* var_scale = (const float*)d_in[1];
    const int*   idx       = (const int*)d_in[2];
    const float* upd       = (const float*)d_in[3];   // fp16 transported as f32
    const float* scl       = (const float*)d_in[4];   // fp16 transported as f32

    float* y    = (float*)d_out;                      // y (f32) [N*D]
    float* outf = y + (size_t)N_ROWS * D_COLS;        // out (f32) [N*D]
    float* scale_out = y + 2 * (size_t)N_ROWS * D_COLS;

    // scratch in the not-yet-written y region: exactly 256 MB
    u32*    packed = (u32*)y;                                   // 128 MB [D][M]
    __half* sumT   = (__half*)((char*)y + (size_t)134217728);   // 128 MB [D][N]
    u32* ws = (u32*)d_ws;

    init_ws_k<<<1, 64, 0, stream>>>(ws);
    t_pack_k<<<8192, 256, 0, stream>>>(idx, upd, scl, packed);
    scatter_q_k<<<4096, 1024, 0, stream>>>(packed, sumT);
    finalize_k<<<8192, 256, 0, stream>>>(var, sumT, var_scale, outf, ws);
    quant_k<<<8192, 256, 0, stream>>>(outf, y, ws, scale_out);
}

// Round 21
// 479.215 us; speedup vs baseline: 1.0142x; 1.0142x over previous
//
#include <hip/hip_runtime.h>
#include <hip/hip_fp16.h>

#define N_ROWS 65536
#define D_COLS 1024
#define M_ROWS 32768
#define QROWS  16384   // rows per scatter pass (64KB f32 LDS)
#define FT     4       // finalize: r-tiles per block (double-buffered)

using u32 = unsigned int;
using u16 = unsigned short;
typedef float f32x4 __attribute__((ext_vector_type(4)));   // native vecs for nontemporal
typedef int   i32x4 __attribute__((ext_vector_type(4)));

static __device__ __forceinline__ __half2 u32_as_half2(u32 w) {
    union { u32 u; __half2 h; } c; c.u = w; return c.h;
}

// ---- ws[0] = 0 (abs-max accumulator) ----
__global__ void init_ws_k(u32* ws) {
    if (threadIdx.x == 0 && blockIdx.x == 0) ws[0] = 0u;
}

// ---- 64x64-tile transpose+pack: packed[j][i] = (u16)idx[i][j] | fp16(upd*scl)<<16 ----
__global__ __launch_bounds__(256) void t_pack_k(const int* __restrict__ idx,
                                                const float* __restrict__ upd,
                                                const float* __restrict__ scl,
                                                u32* __restrict__ packed) {
    __shared__ u32   sidx[64][65];
    __shared__ float supd[64][65];
    const int swz = (int)(blockIdx.x & 7) * 1024 + (int)(blockIdx.x >> 3); // 8192%8==0
    const int i0 = (swz & 511) * 64;              // i-tile INNER (512 i-tiles)
    const int j0 = (swz >> 9) * 64;               // j-tile outer (16 j-tiles)
    const int t = threadIdx.x;

    {
        const int rr = t >> 2, c4 = t & 3;
        const int*   ip = idx + (size_t)(i0 + rr) * D_COLS + j0;
        const float* up = upd + (size_t)(i0 + rr) * D_COLS + j0;
        #pragma unroll
        for (int cq = 0; cq < 4; ++cq) {
            const int jc = cq * 16 + c4 * 4;
            const i32x4 iv = __builtin_nontemporal_load((const i32x4*)(ip + jc));
            const f32x4 uv = __builtin_nontemporal_load((const f32x4*)(up + jc));
            sidx[rr][jc] = (u32)iv.x; sidx[rr][jc+1] = (u32)iv.y;
            sidx[rr][jc+2] = (u32)iv.z; sidx[rr][jc+3] = (u32)iv.w;
            supd[rr][jc] = uv.x; supd[rr][jc+1] = uv.y;
            supd[rr][jc+2] = uv.z; supd[rr][jc+3] = uv.w;
        }
    }
    __syncthreads();

    {
        const int jj = t >> 2, seg = t & 3;
        const __half hs = __float2half(scl[j0 + jj]);   // exact fp16 scale
        u32 w16[16];
        #pragma unroll
        for (int p = 0; p < 16; ++p) {
            const int r = seg * 16 + p;
            const __half hv = __hmul(__float2half(supd[r][jj]), hs);  // fp16 mult = ref
            w16[p] = (sidx[r][jj] & 0xffffu) | ((u32)__half_as_ushort(hv) << 16);
        }
        u32* d = packed + (size_t)(j0 + jj) * M_ROWS + i0 + seg * 16;
        ((uint4*)d)[0] = uint4{w16[0],  w16[1],  w16[2],  w16[3]};
        ((uint4*)d)[1] = uint4{w16[4],  w16[5],  w16[6],  w16[7]};
        ((uint4*)d)[2] = uint4{w16[8],  w16[9],  w16[10], w16[11]};
        ((uint4*)d)[3] = uint4{w16[12], w16[13], w16[14], w16[15]};
    }
}

// ---- per (column j, quarter h): zero 64KB LDS, scan packed column, GUARDED ds_add
//      (33.5M active lane-atomics at ~3.2cy each: the measured wall), fp16 write. ----
__global__ __launch_bounds__(1024) void scatter_q_k(const u32* __restrict__ packed,
                                                    __half* __restrict__ sumT) {
    __shared__ float acc[QROWS];                  // 64 KB -> 2 blocks/CU
    const int bid = (blockIdx.x & 7) * 512 + (blockIdx.x >> 3);  // bijective, 4096%8==0
    const int j = bid >> 2;                       // column 0..1023
    const int h = bid & 3;                        // row quarter
    const int tid = threadIdx.x;

    float4* a4 = (float4*)acc;
    #pragma unroll
    for (int k = 0; k < 4; ++k) a4[k * 1024 + tid] = float4{0.f, 0.f, 0.f, 0.f};

    const i32x4* col4 = (const i32x4*)(packed + (size_t)j * M_ROWS);  // 8192 int4
    __syncthreads();

    #pragma unroll
    for (int k = 0; k < 8; ++k) {
        const i32x4 e4 = col4[k * 1024 + tid];
        const u32 e[4] = {(u32)e4.x, (u32)e4.y, (u32)e4.z, (u32)e4.w};
        #pragma unroll
        for (int q = 0; q < 4; ++q) {
            const int r = (int)(e[q] & 0xffffu);
            if ((r >> 14) == h)   // guarded: inactive lanes issue no atomic lane-op
                atomicAdd(&acc[r & (QROWS - 1)],
                          __half2float(__ushort_as_half((u16)(e[q] >> 16))));
        }
    }
    __syncthreads();

    uint4* dst4 = (uint4*)(sumT + (size_t)j * N_ROWS + h * QROWS);
    #pragma unroll
    for (int o = 0; o < 2; ++o) {
        const int base = o * 8192 + tid * 8;
        const float4 f0 = *(const float4*)&acc[base];
        const float4 f1 = *(const float4*)&acc[base + 4];
        const __half2 h0 = __floats2half2_rn(f0.x, f0.y);
        const __half2 h1 = __floats2half2_rn(f0.z, f0.w);
        const __half2 h2 = __floats2half2_rn(f1.x, f1.y);
        const __half2 h3 = __floats2half2_rn(f1.z, f1.w);
        dst4[o * 1024 + tid] = uint4{*(const u32*)&h0, *(const u32*)&h1,
                                     *(const u32*)&h2, *(const u32*)&h3};
    }
}

// ---- finalize: 4 consecutive 128x64 r-tiles per block, double-buffered half2
//      staging (T14 issue-early/write-late): next tile's sumT loads are in flight
//      during the current tile's compute. 35KB LDS -> 4 blocks/CU. ----
__global__ __launch_bounds__(256) void finalize_k(const int* __restrict__ var,
                                                  const __half* __restrict__ sumT,
                                                  const float* __restrict__ var_scale,
                                                  float* __restrict__ outf,
                                                  u32* __restrict__ ws) {
    __shared__ __half2 smh[2][64][68];            // [buf][row-pair][col], 2x17.4 KB
    __shared__ float wmax[4];
    const int swz = (int)(blockIdx.x & 7) * 256 + (int)(blockIdx.x >> 3); // 2048%8==0
    const int ub = (swz & 127) * (FT * 128);      // unit base row (128 units of 512)
    const int j0 = (swz >> 7) * 64;               // 16 j-tiles; XCD owns 128-col slab
    const int tid = threadIdx.x;
    const float s = var_scale[0];
    const int jj = tid >> 2, seg = tid & 3;

    i32x4 rg[4];
    {   // prologue: tile 0 -> regs -> smh[0]
        const __half* colp = sumT + (size_t)(j0 + jj) * N_ROWS + ub + seg * 32;
        #pragma unroll
        for (int q = 0; q < 4; ++q)
            rg[q] = __builtin_nontemporal_load((const i32x4*)colp + q);
        #pragma unroll
        for (int q = 0; q < 4; ++q) {
            const u32 w0 = (u32)rg[q].x, w1 = (u32)rg[q].y;
            const u32 w2 = (u32)rg[q].z, w3 = (u32)rg[q].w;
            smh[0][seg * 16 + q * 4 + 0][jj] = u32_as_half2(w0);
            smh[0][seg * 16 + q * 4 + 1][jj] = u32_as_half2(w1);
            smh[0][seg * 16 + q * 4 + 2][jj] = u32_as_half2(w2);
            smh[0][seg * 16 + q * 4 + 3][jj] = u32_as_half2(w3);
        }
    }
    __syncthreads();

    float m = 0.f;
    #pragma unroll
    for (int t = 0; t < FT; ++t) {
        const int cur = t & 1;
        const int r0 = ub + t * 128;
        if (t + 1 < FT) {   // issue next tile's staging loads BEFORE compute
            const __half* colp = sumT + (size_t)(j0 + jj) * N_ROWS + (r0 + 128) + seg * 32;
            #pragma unroll
            for (int q = 0; q < 4; ++q)
                rg[q] = __builtin_nontemporal_load((const i32x4*)colp + q);
        }
        #pragma unroll
        for (int k = 0; k < 8; ++k) {
            const int l = k * 256 + tid;          // 0..2047 int4 units
            const int rr = l >> 4, c4 = l & 15;
            const i32x4 v = __builtin_nontemporal_load(
                (const i32x4*)(var + (size_t)(r0 + rr) * D_COLS + j0) + c4);
            const __half2* hp = &smh[cur][rr >> 1][c4 * 4];
            const __half2 p0 = hp[0], p1 = hp[1], p2 = hp[2], p3 = hp[3];
            const bool hi = (rr & 1) != 0;
            float4 o;
            o.x = (float)v.x * s + (hi ? __high2float(p0) : __low2float(p0));
            o.y = (float)v.y * s + (hi ? __high2float(p1) : __low2float(p1));
            o.z = (float)v.z * s + (hi ? __high2float(p2) : __low2float(p2));
            o.w = (float)v.w * s + (hi ? __high2float(p3) : __low2float(p3));
            ((float4*)(outf + (size_t)(r0 + rr) * D_COLS + j0))[c4] = o;
            m = fmaxf(m, fmaxf(fmaxf(fabsf(o.x), fabsf(o.y)),
                               fmaxf(fabsf(o.z), fabsf(o.w))));
        }
        __syncthreads();                           // all reads of smh[cur] done
        if (t + 1 < FT) {                          // write-late into the other buffer
            #pragma unroll
            for (int q = 0; q < 4; ++q) {
                const u32 w0 = (u32)rg[q].x, w1 = (u32)rg[q].y;
                const u32 w2 = (u32)rg[q].z, w3 = (u32)rg[q].w;
                smh[cur ^ 1][seg * 16 + q * 4 + 0][jj] = u32_as_half2(w0);
                smh[cur ^ 1][seg * 16 + q * 4 + 1][jj] = u32_as_half2(w1);
                smh[cur ^ 1][seg * 16 + q * 4 + 2][jj] = u32_as_half2(w2);
                smh[cur ^ 1][seg * 16 + q * 4 + 3][jj] = u32_as_half2(w3);
            }
            __syncthreads();
        }
    }
    for (int off = 32; off; off >>= 1) m = fmaxf(m, __shfl_xor(m, off));
    if ((tid & 63) == 0) wmax[tid >> 6] = m;
    __syncthreads();
    if (tid == 0) {
        m = fmaxf(fmaxf(wmax[0], wmax[1]), fmaxf(wmax[2], wmax[3]));
        atomicMax(ws, __float_as_uint(m));
    }
}

// ---- y = clip(rint(out*127/max)): R18's forward tile map (best measured) ----
__global__ __launch_bounds__(256) void quant_k(const float* __restrict__ outf,
                                               float* __restrict__ y,
                                               const u32* __restrict__ ws,
                                               float* __restrict__ scale_out) {
    const float mx = __uint_as_float(ws[0]);
    const float inv = 127.0f / mx;
    const int swz = (int)(blockIdx.x & 7) * 1024 + (int)(blockIdx.x >> 3);
    const int r0 = (swz & 511) * 128;
    const int j0 = (swz >> 9) * 64;
    const int tid = threadIdx.x;
    if (blockIdx.x == 0 && tid == 0) scale_out[0] = mx / 127.0f;
    #pragma unroll
    for (int k = 0; k < 8; ++k) {
        const int l = k * 256 + tid;
        const int rr = l >> 4, c4 = l & 15;
        const size_t off = (size_t)(r0 + rr) * D_COLS + j0 + c4 * 4;
        const float4 v = *(const float4*)(outf + off);
        f32x4 o;
        o.x = fminf(fmaxf(rintf(v.x * inv), -128.f), 127.f);
        o.y = fminf(fmaxf(rintf(v.y * inv), -128.f), 127.f);
        o.z = fminf(fmaxf(rintf(v.z * inv), -128.f), 127.f);
        o.w = fminf(fmaxf(rintf(v.w * inv), -128.f), 127.f);
        __builtin_nontemporal_store(o, (f32x4*)(y + off));   // y never re-read
    }
}

extern "C" void kernel_launch(void* const* d_in, const int* in_sizes, int n_in,
                              void* d_out, int out_size, void* d_ws, size_t ws_size,
                              hipStream_t stream) {
    const int*   var       = (const int*)d_in[0];     // int8 transported as int32
    const float* var_scale = (const float*)d_in[1];
    const int*   idx       = (const int*)d_in[2];
    const float* upd       = (const float*)d_in[3];   // fp16 transported as f32
    const float* scl       = (const float*)d_in[4];   // fp16 transported as f32

    float* y    = (float*)d_out;                      // y (f32) [N*D]
    float* outf = y + (size_t)N_ROWS * D_COLS;        // out (f32) [N*D]
    float* scale_out = y + 2 * (size_t)N_ROWS * D_COLS;

    // scratch in the not-yet-written y region: exactly 256 MB
    u32*    packed = (u32*)y;                                   // 128 MB [D][M]
    __half* sumT   = (__half*)((char*)y + (size_t)134217728);   // 128 MB [D][N]
    u32* ws = (u32*)d_ws;

    init_ws_k<<<1, 64, 0, stream>>>(ws);
    t_pack_k<<<8192, 256, 0, stream>>>(idx, upd, scl, packed);
    scatter_q_k<<<4096, 1024, 0, stream>>>(packed, sumT);
    finalize_k<<<2048, 256, 0, stream>>>(var, sumT, var_scale, outf, ws);
    quant_k<<<8192, 256, 0, stream>>>(outf, y, ws, scale_out);
}